// Round 12
// baseline (157.058 us; speedup 1.0000x reference)
//
#include <hip/hip_runtime.h>
#include <hip/hip_bf16.h>

// B=8 IC=8 ID=16 OC=8 OD=16 H=W=32 K=3 ITER=3
// conv as MFMA GEMM per image: A=tw (512 co4 x 576 k), B=im2col(x) (576 k x 1024 pos)
// p stored route-friendly: p2[r][y][ch][n][c][x16] (r=co4&3, c=co4>>2, ch=x>>4), bf16, 64MB
// BN stats fused into k_mconv epilogue as non-atomic per-block partials.
// v output: (B, OC, OD, 4, H, W) = 4,194,304 fp32; entropy scalar at out[4194304]

typedef short bf16x8 __attribute__((ext_vector_type(8)));
typedef float f32x4 __attribute__((ext_vector_type(4)));
typedef unsigned int u32x2 __attribute__((ext_vector_type(2)));

__device__ inline float bf2f(unsigned int u) {
    union { unsigned int i; float f; } x;
    x.i = u << 16;
    return x.f;
}
__device__ inline unsigned short f2bf(float f) {
    union { float f; unsigned int u; } x;
    x.f = f;
    unsigned int r = x.u + 0x7fffu + ((x.u >> 16) & 1u);
    return (unsigned short)(r >> 16);
}

// cross-lane helpers (all-lanes-active contexts only)
__device__ inline float dppx1(float x) {   // lane^1 (quad_perm 1,0,3,2)
    return __int_as_float(__builtin_amdgcn_update_dpp(0, __float_as_int(x), 0xB1, 0xF, 0xF, false));
}
__device__ inline float dppx2(float x) {   // lane^2 (quad_perm 2,3,0,1)
    return __int_as_float(__builtin_amdgcn_update_dpp(0, __float_as_int(x), 0x4E, 0xF, 0xF, false));
}
__device__ inline float dppx8(float x) {   // lane^8 (row_ror:8 within 16-lane row) - VALU
    return __int_as_float(__builtin_amdgcn_update_dpp(0, __float_as_int(x), 0x128, 0xF, 0xF, false));
}
template <int PATT>
__device__ inline float swzf(float x) {
    return __int_as_float(__builtin_amdgcn_ds_swizzle(__float_as_int(x), PATT));
}
#define SWZ4  0x101F
__device__ inline float psum16(float x) {  // x + x[lane^16] via permlane16_swap - VALU
    u32x2 r = __builtin_amdgcn_permlane16_swap(__float_as_uint(x), __float_as_uint(x), false, false);
    return __uint_as_float(r[0]) + __uint_as_float(r[1]);
}
__device__ inline float psum32(float x) {  // x + x[lane^32] via permlane32_swap - VALU
    u32x2 r = __builtin_amdgcn_permlane32_swap(__float_as_uint(x), __float_as_uint(x), false, false);
    return __uint_as_float(r[0]) + __uint_as_float(r[1]);
}

// ---------------- kernel 1: transformed weights, bf16, pre-swizzled ----------------
// twb[tap][co4][ci'] : [9][512][64] bf16 ; stored ci' = ci ^ ((co4&7)<<3)
__global__ __launch_bounds__(256) void k_twb(const float* __restrict__ w,
                                             unsigned short* __restrict__ twb) {
    int idx = blockIdx.x * 256 + threadIdx.x;
    int tap = idx >> 15;
    int rem = idx & 32767;
    int co4 = rem >> 6;
    int cst = rem & 63;
    int ci = cst ^ ((co4 & 7) << 3);
    int r = co4 & 3, co = co4 >> 2;
    int s = ci & 3, cicap = ci >> 2;
    int ky = tap / 3, kx = tap % 3;
    int sy, sx;
    switch (r) {
        case 0: sy = ky;      sx = kx;      break;
        case 1: sy = kx;      sx = 2 - ky;  break;
        case 2: sy = 2 - ky;  sx = 2 - kx;  break;
        default: sy = 2 - kx; sx = ky;      break;
    }
    int ss = (s - r) & 3;
    twb[idx] = f2bf(w[(((co * 16 + cicap) * 4 + ss) * 3 + sy) * 3 + sx]);
}

// ---------------- kernel 2: pad + transpose + bf16 + swizzle the input ----------------
// xpad[n][yy][xx][ci'] : [64][34][34][64] bf16 ; ci' = ci ^ ((xx&7)<<3); borders pre-zeroed
__global__ __launch_bounds__(256) void k_prep(const float* __restrict__ xf,
                                              unsigned short* __restrict__ xpad) {
    int n = blockIdx.x >> 5, y = blockIdx.x & 31;
    int tid = threadIdx.x;
    __shared__ float tile[64][33];
#pragma unroll
    for (int it = 0; it < 8; ++it) {
        int ci = it * 8 + (tid >> 5), x = tid & 31;
        tile[ci][x] = xf[((n * 64 + ci) * 32 + y) * 32 + x];
    }
    __syncthreads();
    int xx = 1 + (tid >> 3), g = tid & 7;
    int x = xx - 1;
    int lg = g ^ (xx & 7);
    unsigned short vals[8];
#pragma unroll
    for (int j = 0; j < 8; ++j) vals[j] = f2bf(tile[lg * 8 + j][x]);
    uint4 pk;
    pk.x = (unsigned)vals[0] | ((unsigned)vals[1] << 16);
    pk.y = (unsigned)vals[2] | ((unsigned)vals[3] << 16);
    pk.z = (unsigned)vals[4] | ((unsigned)vals[5] << 16);
    pk.w = (unsigned)vals[6] | ((unsigned)vals[7] << 16);
    *reinterpret_cast<uint4*>(&xpad[(n * 34 + (y + 1)) * 2176 + xx * 64 + g * 8]) = pk;
}

// ---------------- kernel 3: MFMA conv + fused non-atomic BN partials ----------------
// grid (64 n, 8 yt, 4 cot), 256 threads = 4 waves in 2x2
// wave tile: 64 co4 x 64 pos (4x4 frags 16x16), K = 9 taps x 2 steps of 32
__global__ __launch_bounds__(256, 3) void k_mconv(const unsigned short* __restrict__ xpad,
                                                  const unsigned short* __restrict__ twb,
                                                  unsigned short* __restrict__ p2,
                                                  float* __restrict__ ps) {
    int n = blockIdx.x, yt = blockIdx.y, cot = blockIdx.z;
    int y0 = yt * 4;
    int tid = threadIdx.x, lane = tid & 63, wave = tid >> 6;
    int wm = (wave >> 1) * 64, wn = (wave & 1) * 64;
    int p15 = lane & 15, hi = lane >> 4;

    __shared__ unsigned short xs[6 * 34 * 64];   // 26112 B
    __shared__ unsigned short wA[128 * 64];      // 16384 B

    {
        const uint4* src = reinterpret_cast<const uint4*>(xpad + (n * 34 + y0) * 2176);
        uint4* dst = reinterpret_cast<uint4*>(xs);
        for (int t = tid; t < 1632; t += 256) dst[t] = src[t];
    }

    f32x4 acc[4][4];
#pragma unroll
    for (int mf = 0; mf < 4; ++mf)
#pragma unroll
        for (int nf = 0; nf < 4; ++nf) acc[mf][nf] = (f32x4){0.f, 0.f, 0.f, 0.f};

    int yl[4], xb[4];
#pragma unroll
    for (int nf = 0; nf < 4; ++nf) {
        int posl = wn + nf * 16 + p15;
        yl[nf] = posl >> 5;
        xb[nf] = posl & 31;
    }

    for (int tap = 0; tap < 9; ++tap) {
        __syncthreads();
        {
            const uint4* wsrc = reinterpret_cast<const uint4*>(twb + (tap * 512 + cot * 128) * 64);
            uint4* wdst = reinterpret_cast<uint4*>(wA);
            for (int t = tid; t < 1024; t += 256) wdst[t] = wsrc[t];
        }
        __syncthreads();

        int ky = tap / 3, kx = tap % 3;

        bf16x8 a[4][2], b[4][2];
#pragma unroll
        for (int mf = 0; mf < 4; ++mf) {
            int co4l = wm + mf * 16 + p15;
#pragma unroll
            for (int s = 0; s < 2; ++s) {
                int cig = hi + s * 4;
                a[mf][s] = *reinterpret_cast<const bf16x8*>(
                    &wA[co4l * 64 + ((cig ^ (co4l & 7)) << 3)]);
            }
        }
#pragma unroll
        for (int nf = 0; nf < 4; ++nf) {
            int row = yl[nf] + ky, col = xb[nf] + kx;
#pragma unroll
            for (int s = 0; s < 2; ++s) {
                int cig = hi + s * 4;
                b[nf][s] = *reinterpret_cast<const bf16x8*>(
                    &xs[(row * 34 + col) * 64 + ((cig ^ (col & 7)) << 3)]);
            }
        }
#pragma unroll
        for (int s = 0; s < 2; ++s)
#pragma unroll
            for (int mf = 0; mf < 4; ++mf)
#pragma unroll
                for (int nf = 0; nf < 4; ++nf)
                    acc[mf][nf] = __builtin_amdgcn_mfma_f32_16x16x32_bf16(
                        a[mf][s], b[nf][s], acc[mf][nf], 0, 0, 0);
    }

    // epilogue -> p2[r][y][ch][n][c][x16] + per-block BN partials (NO atomics)
    int blkLin = cot * 512 + yt * 64 + n;
#pragma unroll
    for (int mf = 0; mf < 4; ++mf) {
        int c = cot * 32 + (wm >> 2) + mf * 4 + hi;
        float s = 0.f, s2 = 0.f;
#pragma unroll
        for (int nf = 0; nf < 4; ++nf) {
            int posl = wn + nf * 16 + p15;
            int y = y0 + (posl >> 5);
            int ch = (posl >> 4) & 1;
#pragma unroll
            for (int reg = 0; reg < 4; ++reg) {
                float v = acc[mf][nf][reg];
                s += v; s2 += v * v;
                int idx = ((((reg * 32 + y) * 2 + ch) * 64 + n) * 128 + c) * 16 + p15;
                p2[idx] = f2bf(v);
            }
        }
        // reduce over the 16 pos-lanes sharing (hi): lane bits 0-3
        s  += __shfl_xor(s, 1);  s  += __shfl_xor(s, 2);  s  += __shfl_xor(s, 4);  s  += __shfl_xor(s, 8);
        s2 += __shfl_xor(s2, 1); s2 += __shfl_xor(s2, 2); s2 += __shfl_xor(s2, 4); s2 += __shfl_xor(s2, 8);
        if (p15 == 0) {
            int cl = (wm >> 2) + mf * 4 + hi;
            float* q = ps + ((blkLin * 2 + (wave & 1)) * 32 + cl) * 2;
            q[0] = s;
            q[1] = s2;
        }
    }
}

// ---------------- kernel 4: finalize affine coefs from block partials ----------------
// ps[blk][wn][cl][2], blk = cot*512 + yt*64 + n; channel c -> blk range [cot*512, +512)
__global__ __launch_bounds__(256) void k_ab(const float* __restrict__ ps,
                                            const float* __restrict__ gamma,
                                            const float* __restrict__ beta,
                                            float* __restrict__ ab) {
    int c = threadIdx.x >> 1, h = threadIdx.x & 1;
    int cot = c >> 5, cl = c & 31;
    float S = 0.f, S2 = 0.f;
    int blk0 = cot * 512 + h * 256;
    for (int bb = 0; bb < 256; ++bb) {
        const float* q = ps + (((blk0 + bb) * 2) * 32 + cl) * 2;
        S  += q[0] + q[64];     // wn=0, wn=1 (wn stride = 64 floats)
        S2 += q[1] + q[65];
    }
    S  += __shfl_xor(S, 1);
    S2 += __shfl_xor(S2, 1);
    if (h == 0) {
        float mean = S * (1.f / 262144.f);
        float var = S2 * (1.f / 262144.f) - mean * mean;
        float A = gamma[c] * rsqrtf(var + 1e-5f);
        ab[2 * c] = A;
        ab[2 * c + 1] = beta[c] - mean * A;
    }
}

// ---------------- kernel 5: fused routing + entropy (VALU cross-lane reductions) ----------------
// grid 2048; bid: k=bid&7, ch=(bid>>3)&1, unit=(bid>>4)*8+k
// unit: b = u>>7, r = (u>>5)&3, y = u&31. Block region = 32KB contiguous in p2.
// Tl2 lane index bank-swizzled by od<<1: write ls^(od<<1), read lane^(od<<1) -> 2-way max.
__global__ __launch_bounds__(256, 4) void k_route(const unsigned short* __restrict__ pp,
                                                  const float* __restrict__ ab,
                                                  float* __restrict__ out,
                                                  float* __restrict__ ent_out) {
    int bid = blockIdx.x;
    int u = ((bid >> 4) << 3) + (bid & 7);
    int ch = (bid >> 3) & 1;
    int y = u & 31, r = (u >> 5) & 3, b = u >> 7;
    int x0 = ch * 16;
    int tid = threadIdx.x;
    int wave = tid >> 6, lane = tid & 63;
    int i_l = lane >> 3, oc_l = lane & 7;

    __shared__ unsigned int Tl2[16][8][64];      // [od][x-pair][lane'(swz)]  32 KB
    __shared__ unsigned short vst[8][16][18];    // [oc][od][x+pad]           4.5 KB
    __shared__ float ered[4];

    // ---- stage: one contiguous 32KB slab; slot = i*256 + c*2 + half ----
    const uint4* src = reinterpret_cast<const uint4*>(pp) +
                       (((((r * 32 + y) * 2 + ch) * 64) + b * 8) << 8);
#pragma unroll
    for (int pass = 0; pass < 8; ++pass) {
        int slot = pass * 256 + tid;
        int il = slot >> 8, c = (slot >> 1) & 127, half = slot & 1;
        int od = c & 15, oo = c >> 4;
        int ls = (il * 8 + oo) ^ (od << 1);      // bank-swizzled lane slot
        float A = ab[2 * c], Bv = ab[2 * c + 1];
        uint4 d = src[slot];
        unsigned wds[4] = {d.x, d.y, d.z, d.w};
#pragma unroll
        for (int jj = 0; jj < 4; ++jj) {
            float tlo = A * bf2f(wds[jj] & 0xffffu) + Bv;
            float thi = A * bf2f(wds[jj] >> 16) + Bv;
            Tl2[od][half * 4 + jj][ls] = (unsigned)f2bf(tlo) | ((unsigned)f2bf(thi) << 16);
        }
    }
    __syncthreads();

    float e_acc = 0.f;

    for (int q = 0; q < 2; ++q) {
        int p2i = wave + q * 4;
        float t0[16], t1[16];
#pragma unroll
        for (int od = 0; od < 16; ++od) {
            unsigned pr = Tl2[od][p2i][lane ^ (od << 1)];
            t0[od] = bf2f(pr & 0xffffu);
            t1[od] = bf2f(pr >> 16);
        }

        float b0 = 0.f, b1 = 0.f, c0, c1, sc0 = 0.f, sc1 = 0.f;
        float s0[16], s1[16];
        for (int it = 0; it < 3; ++it) {
            float m0 = b0, m1 = b1;
            m0 = fmaxf(m0, dppx1(m0));      m1 = fmaxf(m1, dppx1(m1));
            m0 = fmaxf(m0, dppx2(m0));      m1 = fmaxf(m1, dppx2(m1));
            m0 = fmaxf(m0, swzf<SWZ4>(m0)); m1 = fmaxf(m1, swzf<SWZ4>(m1));
            float e0 = __expf(b0 - m0), e1 = __expf(b1 - m1);
            float se0 = e0, se1 = e1;
            se0 += dppx1(se0);      se1 += dppx1(se1);
            se0 += dppx2(se0);      se1 += dppx2(se1);
            se0 += swzf<SWZ4>(se0); se1 += swzf<SWZ4>(se1);
            c0 = e0 * __builtin_amdgcn_rcpf(se0);
            c1 = e1 * __builtin_amdgcn_rcpf(se1);
            // sum over i (lane bits 3,4,5) - all VALU now
            float n20 = 0.f, n21 = 0.f;
#pragma unroll
            for (int od = 0; od < 16; ++od) {
                float v0 = c0 * t0[od], v1 = c1 * t1[od];
                v0 += dppx8(v0);        v1 += dppx8(v1);
                v0 = psum16(v0);        v1 = psum16(v1);
                v0 = psum32(v0);        v1 = psum32(v1);
                s0[od] = v0;            s1[od] = v1;
                n20 += v0 * v0;         n21 += v1 * v1;
            }
            float nr0 = sqrtf(n20), nr1 = sqrtf(n21);
            sc0 = n20 * __builtin_amdgcn_rcpf((1.f + n20) * (nr0 + 1e-8f));
            sc1 = n21 * __builtin_amdgcn_rcpf((1.f + n21) * (nr1 + 1e-8f));
            if (it < 2) {
                float a0 = 0.f, a1 = 0.f;
#pragma unroll
                for (int od = 0; od < 16; ++od) {
                    a0 += t0[od] * s0[od];
                    a1 += t1[od] * s1[od];
                }
                b0 += a0 * sc0;
                b1 += a1 * sc1;
            }
        }
        e_acc += -c0 * __logf(c0) - c1 * __logf(c1);
        if (i_l == 0) {
#pragma unroll
            for (int od = 0; od < 16; ++od) {
                vst[oc_l][od][2 * p2i]     = f2bf(sc0 * s0[od]);
                vst[oc_l][od][2 * p2i + 1] = f2bf(sc1 * s1[od]);
            }
        }
    }

    e_acc += dppx1(e_acc);
    e_acc += dppx2(e_acc);
    e_acc += swzf<SWZ4>(e_acc);
    e_acc += dppx8(e_acc);
    e_acc = psum16(e_acc);
    e_acc = psum32(e_acc);
    if (lane == 0) ered[wave] = e_acc;
    __syncthreads();

    {
        int xx = tid & 15, od = (tid >> 4) & 15;
#pragma unroll
        for (int oc = 0; oc < 8; ++oc) {
            out[((((b * 8 + oc) * 16 + od) * 4 + r) * 32 + y) * 32 + x0 + xx] =
                bf2f(vst[oc][od][xx]);
        }
    }
    if (tid == 0) {
        float tot = ered[0] + ered[1] + ered[2] + ered[3];
        atomicAdd(ent_out, tot * (1.0f / (2.0794415416798357f * 32768.0f)));
    }
}

extern "C" void kernel_launch(void* const* d_in, const int* in_sizes, int n_in,
                              void* d_out, int out_size, void* d_ws, size_t ws_size,
                              hipStream_t stream) {
    const float* x     = (const float*)d_in[0];  // (8,8,16,4,32,32)
    const float* w     = (const float*)d_in[1];  // (128,16,4,3,3)
    const float* gamma = (const float*)d_in[2];  // (128)
    const float* beta  = (const float*)d_in[3];  // (128)
    float* out = (float*)d_out;                  // 4,194,304 v + 1 entropy

    char* ws = (char*)d_ws;
    unsigned short* p2   = (unsigned short*)ws;                                  // 67,108,864 B
    unsigned short* xpad = (unsigned short*)(ws + 67108864);                     //  9,469,952 B
    unsigned short* twb  = (unsigned short*)(ws + 67108864 + 9469952);           //    589,824 B
    float* ab            = (float*)(ws + 67108864 + 9469952 + 589824);           //      1,024 B
    float* ps            = (float*)(ws + 67108864 + 9469952 + 589824 + 1024);    //  1,048,576 B

    hipMemsetAsync(out + 4194304, 0, 4, stream);
    hipMemsetAsync(xpad, 0, 9469952, stream);

    k_twb<<<1152, 256, 0, stream>>>(w, twb);
    k_prep<<<2048, 256, 0, stream>>>(x, xpad);

    dim3 gconv(64, 8, 4);
    k_mconv<<<gconv, 256, 0, stream>>>(xpad, twb, p2, ps);

    k_ab<<<1, 256, 0, stream>>>(ps, gamma, beta, ab);

    k_route<<<2048, 256, 0, stream>>>(p2, ab, out, out + 4194304);
}

// Round 13
// 150.023 us; speedup vs baseline: 1.0469x; 1.0469x over previous
//
#include <hip/hip_runtime.h>
#include <hip/hip_bf16.h>

// B=8 IC=8 ID=16 OC=8 OD=16 H=W=32 K=3 ITER=3
// conv as MFMA GEMM per image: A=tw (512 co4 x 576 k), B=im2col(x) (576 k x 1024 pos)
// p stored route-friendly: p2[r][y][ch][n][c][x16] (r=co4&3, c=co4>>2, ch=x>>4), bf16, 64MB
// v output: (B, OC, OD, 4, H, W) = 4,194,304 fp32; entropy scalar at out[4194304]

typedef short bf16x8 __attribute__((ext_vector_type(8)));
typedef float f32x4 __attribute__((ext_vector_type(4)));
typedef unsigned int u32x2 __attribute__((ext_vector_type(2)));

__device__ inline float bf2f(unsigned int u) {
    union { unsigned int i; float f; } x;
    x.i = u << 16;
    return x.f;
}
__device__ inline unsigned short f2bf(float f) {
    union { float f; unsigned int u; } x;
    x.f = f;
    unsigned int r = x.u + 0x7fffu + ((x.u >> 16) & 1u);
    return (unsigned short)(r >> 16);
}

// cross-lane helpers (all-lanes-active contexts only); all proven in r11/r12 passes
__device__ inline float dppx1(float x) {   // lane^1
    return __int_as_float(__builtin_amdgcn_update_dpp(0, __float_as_int(x), 0xB1, 0xF, 0xF, false));
}
__device__ inline float dppx2(float x) {   // lane^2
    return __int_as_float(__builtin_amdgcn_update_dpp(0, __float_as_int(x), 0x4E, 0xF, 0xF, false));
}
__device__ inline float dppx8(float x) {   // lane^8 (row_ror:8) - VALU
    return __int_as_float(__builtin_amdgcn_update_dpp(0, __float_as_int(x), 0x128, 0xF, 0xF, false));
}
template <int PATT>
__device__ inline float swzf(float x) {
    return __int_as_float(__builtin_amdgcn_ds_swizzle(__float_as_int(x), PATT));
}
#define SWZ4  0x101F
__device__ inline float psum16(float x) {  // x + x[lane^16] - VALU
    u32x2 r = __builtin_amdgcn_permlane16_swap(__float_as_uint(x), __float_as_uint(x), false, false);
    return __uint_as_float(r[0]) + __uint_as_float(r[1]);
}
__device__ inline float psum32(float x) {  // x + x[lane^32] - VALU
    u32x2 r = __builtin_amdgcn_permlane32_swap(__float_as_uint(x), __float_as_uint(x), false, false);
    return __uint_as_float(r[0]) + __uint_as_float(r[1]);
}

// ---------------- kernel 1: transformed weights, bf16, pre-swizzled ----------------
// twb[tap][co4][ci'] : [9][512][64] bf16 ; stored ci' = ci ^ ((co4&7)<<3)
__global__ __launch_bounds__(256) void k_twb(const float* __restrict__ w,
                                             unsigned short* __restrict__ twb) {
    int idx = blockIdx.x * 256 + threadIdx.x;
    int tap = idx >> 15;
    int rem = idx & 32767;
    int co4 = rem >> 6;
    int cst = rem & 63;
    int ci = cst ^ ((co4 & 7) << 3);
    int r = co4 & 3, co = co4 >> 2;
    int s = ci & 3, cicap = ci >> 2;
    int ky = tap / 3, kx = tap % 3;
    int sy, sx;
    switch (r) {
        case 0: sy = ky;      sx = kx;      break;
        case 1: sy = kx;      sx = 2 - ky;  break;
        case 2: sy = 2 - ky;  sx = 2 - kx;  break;
        default: sy = 2 - kx; sx = ky;      break;
    }
    int ss = (s - r) & 3;
    twb[idx] = f2bf(w[(((co * 16 + cicap) * 4 + ss) * 3 + sy) * 3 + sx]);
}

// ---------------- kernel 2: pad + transpose + bf16 + swizzle the input ----------------
// xpad[n][yy][xx][ci'] : [64][34][34][64] bf16 ; ci' = ci ^ ((xx&7)<<3); borders pre-zeroed
__global__ __launch_bounds__(256) void k_prep(const float* __restrict__ xf,
                                              unsigned short* __restrict__ xpad) {
    int n = blockIdx.x >> 5, y = blockIdx.x & 31;
    int tid = threadIdx.x;
    __shared__ float tile[64][33];
#pragma unroll
    for (int it = 0; it < 8; ++it) {
        int ci = it * 8 + (tid >> 5), x = tid & 31;
        tile[ci][x] = xf[((n * 64 + ci) * 32 + y) * 32 + x];
    }
    __syncthreads();
    int xx = 1 + (tid >> 3), g = tid & 7;
    int x = xx - 1;
    int lg = g ^ (xx & 7);
    unsigned short vals[8];
#pragma unroll
    for (int j = 0; j < 8; ++j) vals[j] = f2bf(tile[lg * 8 + j][x]);
    uint4 pk;
    pk.x = (unsigned)vals[0] | ((unsigned)vals[1] << 16);
    pk.y = (unsigned)vals[2] | ((unsigned)vals[3] << 16);
    pk.z = (unsigned)vals[4] | ((unsigned)vals[5] << 16);
    pk.w = (unsigned)vals[6] | ((unsigned)vals[7] << 16);
    *reinterpret_cast<uint4*>(&xpad[(n * 34 + (y + 1)) * 2176 + xx * 64 + g * 8]) = pk;
}

// ---------------- kernel 3: MFMA conv (round-11 proven; DO NOT TOUCH) ----------------
// grid (64 n, 8 yt, 4 cot), 256 threads = 4 waves in 2x2
// wave tile: 64 co4 x 64 pos (4x4 frags 16x16), K = 9 taps x 2 steps of 32
__global__ __launch_bounds__(256, 3) void k_mconv(const unsigned short* __restrict__ xpad,
                                                  const unsigned short* __restrict__ twb,
                                                  unsigned short* __restrict__ p2) {
    int n = blockIdx.x, yt = blockIdx.y, cot = blockIdx.z;
    int y0 = yt * 4;
    int tid = threadIdx.x, lane = tid & 63, wave = tid >> 6;
    int wm = (wave >> 1) * 64, wn = (wave & 1) * 64;
    int p15 = lane & 15, hi = lane >> 4;

    __shared__ unsigned short xs[6 * 34 * 64];   // 26112 B
    __shared__ unsigned short wA[128 * 64];      // 16384 B

    {
        const uint4* src = reinterpret_cast<const uint4*>(xpad + (n * 34 + y0) * 2176);
        uint4* dst = reinterpret_cast<uint4*>(xs);
        for (int t = tid; t < 1632; t += 256) dst[t] = src[t];
    }

    f32x4 acc[4][4];
#pragma unroll
    for (int mf = 0; mf < 4; ++mf)
#pragma unroll
        for (int nf = 0; nf < 4; ++nf) acc[mf][nf] = (f32x4){0.f, 0.f, 0.f, 0.f};

    int yl[4], xb[4];
#pragma unroll
    for (int nf = 0; nf < 4; ++nf) {
        int posl = wn + nf * 16 + p15;
        yl[nf] = posl >> 5;
        xb[nf] = posl & 31;
    }

    for (int tap = 0; tap < 9; ++tap) {
        __syncthreads();
        {
            const uint4* wsrc = reinterpret_cast<const uint4*>(twb + (tap * 512 + cot * 128) * 64);
            uint4* wdst = reinterpret_cast<uint4*>(wA);
            for (int t = tid; t < 1024; t += 256) wdst[t] = wsrc[t];
        }
        __syncthreads();

        int ky = tap / 3, kx = tap % 3;

        bf16x8 a[4][2], b[4][2];
#pragma unroll
        for (int mf = 0; mf < 4; ++mf) {
            int co4l = wm + mf * 16 + p15;
#pragma unroll
            for (int s = 0; s < 2; ++s) {
                int cig = hi + s * 4;
                a[mf][s] = *reinterpret_cast<const bf16x8*>(
                    &wA[co4l * 64 + ((cig ^ (co4l & 7)) << 3)]);
            }
        }
#pragma unroll
        for (int nf = 0; nf < 4; ++nf) {
            int row = yl[nf] + ky, col = xb[nf] + kx;
#pragma unroll
            for (int s = 0; s < 2; ++s) {
                int cig = hi + s * 4;
                b[nf][s] = *reinterpret_cast<const bf16x8*>(
                    &xs[(row * 34 + col) * 64 + ((cig ^ (col & 7)) << 3)]);
            }
        }
#pragma unroll
        for (int s = 0; s < 2; ++s)
#pragma unroll
            for (int mf = 0; mf < 4; ++mf)
#pragma unroll
                for (int nf = 0; nf < 4; ++nf)
                    acc[mf][nf] = __builtin_amdgcn_mfma_f32_16x16x32_bf16(
                        a[mf][s], b[nf][s], acc[mf][nf], 0, 0, 0);
    }

    // epilogue -> p2[r][y][ch][n][c][x16]; r=reg, c=cot*32+(wm>>2)+mf*4+hi, x16=p15
#pragma unroll
    for (int mf = 0; mf < 4; ++mf) {
        int c = cot * 32 + (wm >> 2) + mf * 4 + hi;
#pragma unroll
        for (int nf = 0; nf < 4; ++nf) {
            int posl = wn + nf * 16 + p15;
            int y = y0 + (posl >> 5);
            int ch = (posl >> 4) & 1;
#pragma unroll
            for (int reg = 0; reg < 4; ++reg) {
                int idx = ((((reg * 32 + y) * 2 + ch) * 64 + n) * 128 + c) * 16 + p15;
                p2[idx] = f2bf(acc[mf][nf][reg]);
            }
        }
    }
}

// ---------------- kernel 4a: BN partial sums over p2, fully coalesced ----------------
__global__ __launch_bounds__(256) void k_stats1(const unsigned short* __restrict__ pp,
                                                float* __restrict__ ps) {
    int blk = blockIdx.x, tid = threadIdx.x;
    const uint4* base = reinterpret_cast<const uint4*>(pp) + blk * 8192;
    float s = 0.f, s2 = 0.f;
#pragma unroll 4
    for (int k = 0; k < 32; ++k) {
        uint4 d = base[k * 256 + tid];
        float f;
        f = bf2f(d.x & 0xffffu); s += f; s2 += f * f;
        f = bf2f(d.x >> 16);     s += f; s2 += f * f;
        f = bf2f(d.y & 0xffffu); s += f; s2 += f * f;
        f = bf2f(d.y >> 16);     s += f; s2 += f * f;
        f = bf2f(d.z & 0xffffu); s += f; s2 += f * f;
        f = bf2f(d.z >> 16);     s += f; s2 += f * f;
        f = bf2f(d.w & 0xffffu); s += f; s2 += f * f;
        f = bf2f(d.w >> 16);     s += f; s2 += f * f;
    }
    s  += __shfl_xor(s, 1);
    s2 += __shfl_xor(s2, 1);
    if ((tid & 1) == 0) {
        int c = tid >> 1;
        ps[(blk * 128 + c) * 2]     = s;
        ps[(blk * 128 + c) * 2 + 1] = s2;
    }
}

// ---------------- kernel 4b: finalize affine coefs ----------------
__global__ __launch_bounds__(256) void k_ab(const float* __restrict__ ps,
                                            const float* __restrict__ gamma,
                                            const float* __restrict__ beta,
                                            float* __restrict__ ab) {
    int c = threadIdx.x >> 1, h = threadIdx.x & 1;
    float S = 0.f, S2 = 0.f;
    for (int b = h * 256; b < h * 256 + 256; ++b) {
        S  += ps[(b * 128 + c) * 2];
        S2 += ps[(b * 128 + c) * 2 + 1];
    }
    S  += __shfl_xor(S, 1);
    S2 += __shfl_xor(S2, 1);
    if (h == 0) {
        float mean = S * (1.f / 262144.f);
        float var = S2 * (1.f / 262144.f) - mean * mean;
        float A = gamma[c] * rsqrtf(var + 1e-5f);
        ab[2 * c] = A;
        ab[2 * c + 1] = beta[c] - mean * A;
    }
}

// ---------------- kernel 5: fused routing + entropy, 4-way ILP ----------------
// grid 2048; bid: k=bid&7, ch=(bid>>3)&1, unit=(bid>>4)*8+k
// unit: b = u>>7, r = (u>>5)&3, y = u&31. Block region = 32KB contiguous in p2.
// Each wave runs FOUR positions through the routing chain simultaneously:
//   pair pa=wave -> streams A(x even),B(x odd);  pair pc=wave+4 -> C,D.
__global__ __launch_bounds__(256, 3) void k_route(const unsigned short* __restrict__ pp,
                                                  const float* __restrict__ ab,
                                                  float* __restrict__ out,
                                                  float* __restrict__ ent_out) {
    int bid = blockIdx.x;
    int u = ((bid >> 4) << 3) + (bid & 7);
    int ch = (bid >> 3) & 1;
    int y = u & 31, r = (u >> 5) & 3, b = u >> 7;
    int x0 = ch * 16;
    int tid = threadIdx.x;
    int wave = tid >> 6, lane = tid & 63;
    int i_l = lane >> 3, oc_l = lane & 7;

    __shared__ unsigned int Tl2[16][8][64];      // [od][x-pair][lane'(swz)]  32 KB
    __shared__ unsigned short vst[8][16][18];    // [oc][od][x+pad]           4.5 KB
    __shared__ float ered[4];

    // ---- stage: one contiguous 32KB slab; slot = i*256 + c*2 + half ----
    const uint4* src = reinterpret_cast<const uint4*>(pp) +
                       (((((r * 32 + y) * 2 + ch) * 64) + b * 8) << 8);
#pragma unroll
    for (int pass = 0; pass < 8; ++pass) {
        int slot = pass * 256 + tid;
        int il = slot >> 8, c = (slot >> 1) & 127, half = slot & 1;
        int od = c & 15, oo = c >> 4;
        int ls = (il * 8 + oo) ^ (od << 1);      // bank-swizzled lane slot
        float A = ab[2 * c], Bv = ab[2 * c + 1];
        uint4 d = src[slot];
        unsigned wds[4] = {d.x, d.y, d.z, d.w};
#pragma unroll
        for (int jj = 0; jj < 4; ++jj) {
            float tlo = A * bf2f(wds[jj] & 0xffffu) + Bv;
            float thi = A * bf2f(wds[jj] >> 16) + Bv;
            Tl2[od][half * 4 + jj][ls] = (unsigned)f2bf(tlo) | ((unsigned)f2bf(thi) << 16);
        }
    }
    __syncthreads();

    int pa = wave, pc = wave + 4;
    float tA[16], tB[16], tC[16], tD[16];
#pragma unroll
    for (int od = 0; od < 16; ++od) {
        unsigned prA = Tl2[od][pa][lane ^ (od << 1)];
        unsigned prC = Tl2[od][pc][lane ^ (od << 1)];
        tA[od] = bf2f(prA & 0xffffu);
        tB[od] = bf2f(prA >> 16);
        tC[od] = bf2f(prC & 0xffffu);
        tD[od] = bf2f(prC >> 16);
    }

    float bA = 0.f, bB = 0.f, bC = 0.f, bD = 0.f;
    float cA, cB, cC, cD;
    float scA = 0.f, scB = 0.f, scC = 0.f, scD = 0.f;
    float sA[16], sB[16], sC[16], sD[16];

    for (int it = 0; it < 3; ++it) {
        // softmax over oc (lane bits 0-2), 4 streams
        float mA = bA, mB = bB, mC = bC, mD = bD;
        mA = fmaxf(mA, dppx1(mA)); mB = fmaxf(mB, dppx1(mB)); mC = fmaxf(mC, dppx1(mC)); mD = fmaxf(mD, dppx1(mD));
        mA = fmaxf(mA, dppx2(mA)); mB = fmaxf(mB, dppx2(mB)); mC = fmaxf(mC, dppx2(mC)); mD = fmaxf(mD, dppx2(mD));
        mA = fmaxf(mA, swzf<SWZ4>(mA)); mB = fmaxf(mB, swzf<SWZ4>(mB));
        mC = fmaxf(mC, swzf<SWZ4>(mC)); mD = fmaxf(mD, swzf<SWZ4>(mD));
        float eA = __expf(bA - mA), eB = __expf(bB - mB), eC = __expf(bC - mC), eD = __expf(bD - mD);
        float seA = eA, seB = eB, seC = eC, seD = eD;
        seA += dppx1(seA); seB += dppx1(seB); seC += dppx1(seC); seD += dppx1(seD);
        seA += dppx2(seA); seB += dppx2(seB); seC += dppx2(seC); seD += dppx2(seD);
        seA += swzf<SWZ4>(seA); seB += swzf<SWZ4>(seB); seC += swzf<SWZ4>(seC); seD += swzf<SWZ4>(seD);
        cA = eA * __builtin_amdgcn_rcpf(seA);
        cB = eB * __builtin_amdgcn_rcpf(seB);
        cC = eC * __builtin_amdgcn_rcpf(seC);
        cD = eD * __builtin_amdgcn_rcpf(seD);
        // s = sum_i c*t (lane bits 3,4,5) - all VALU
        float nA = 0.f, nB = 0.f, nC = 0.f, nD = 0.f;
#pragma unroll
        for (int od = 0; od < 16; ++od) {
            float vA = cA * tA[od], vB = cB * tB[od], vC = cC * tC[od], vD = cD * tD[od];
            vA += dppx8(vA); vB += dppx8(vB); vC += dppx8(vC); vD += dppx8(vD);
            vA = psum16(vA); vB = psum16(vB); vC = psum16(vC); vD = psum16(vD);
            vA = psum32(vA); vB = psum32(vB); vC = psum32(vC); vD = psum32(vD);
            sA[od] = vA; sB[od] = vB; sC[od] = vC; sD[od] = vD;
            nA += vA * vA; nB += vB * vB; nC += vC * vC; nD += vD * vD;
        }
        float rA = sqrtf(nA), rB = sqrtf(nB), rC = sqrtf(nC), rD = sqrtf(nD);
        scA = nA * __builtin_amdgcn_rcpf((1.f + nA) * (rA + 1e-8f));
        scB = nB * __builtin_amdgcn_rcpf((1.f + nB) * (rB + 1e-8f));
        scC = nC * __builtin_amdgcn_rcpf((1.f + nC) * (rC + 1e-8f));
        scD = nD * __builtin_amdgcn_rcpf((1.f + nD) * (rD + 1e-8f));
        if (it < 2) {
            float aA = 0.f, aB = 0.f, aC = 0.f, aD = 0.f;
#pragma unroll
            for (int od = 0; od < 16; ++od) {
                aA += tA[od] * sA[od];
                aB += tB[od] * sB[od];
                aC += tC[od] * sC[od];
                aD += tD[od] * sD[od];
            }
            bA += aA * scA; bB += aB * scB; bC += aC * scC; bD += aD * scD;
        }
    }

    float e_acc = -cA * __logf(cA) - cB * __logf(cB) - cC * __logf(cC) - cD * __logf(cD);
    if (i_l == 0) {
#pragma unroll
        for (int od = 0; od < 16; ++od) {
            vst[oc_l][od][2 * pa]     = f2bf(scA * sA[od]);
            vst[oc_l][od][2 * pa + 1] = f2bf(scB * sB[od]);
            vst[oc_l][od][2 * pc]     = f2bf(scC * sC[od]);
            vst[oc_l][od][2 * pc + 1] = f2bf(scD * sD[od]);
        }
    }

    e_acc += dppx1(e_acc);
    e_acc += dppx2(e_acc);
    e_acc += swzf<SWZ4>(e_acc);
    e_acc += dppx8(e_acc);
    e_acc = psum16(e_acc);
    e_acc = psum32(e_acc);
    if (lane == 0) ered[wave] = e_acc;
    __syncthreads();

    {
        int xx = tid & 15, od = (tid >> 4) & 15;
#pragma unroll
        for (int oc = 0; oc < 8; ++oc) {
            out[((((b * 8 + oc) * 16 + od) * 4 + r) * 32 + y) * 32 + x0 + xx] =
                bf2f(vst[oc][od][xx]);
        }
    }
    if (tid == 0) {
        float tot = ered[0] + ered[1] + ered[2] + ered[3];
        atomicAdd(ent_out, tot * (1.0f / (2.0794415416798357f * 32768.0f)));
    }
}

extern "C" void kernel_launch(void* const* d_in, const int* in_sizes, int n_in,
                              void* d_out, int out_size, void* d_ws, size_t ws_size,
                              hipStream_t stream) {
    const float* x     = (const float*)d_in[0];  // (8,8,16,4,32,32)
    const float* w     = (const float*)d_in[1];  // (128,16,4,3,3)
    const float* gamma = (const float*)d_in[2];  // (128)
    const float* beta  = (const float*)d_in[3];  // (128)
    float* out = (float*)d_out;                  // 4,194,304 v + 1 entropy

    char* ws = (char*)d_ws;
    unsigned short* p2   = (unsigned short*)ws;                                  // 67,108,864 B
    unsigned short* xpad = (unsigned short*)(ws + 67108864);                     //  9,469,952 B
    unsigned short* twb  = (unsigned short*)(ws + 67108864 + 9469952);           //    589,824 B
    float* ab            = (float*)(ws + 67108864 + 9469952 + 589824);           //      1,024 B
    float* ps            = (float*)(ws + 67108864 + 9469952 + 589824 + 1024);    //    524,288 B

    hipMemsetAsync(out + 4194304, 0, 4, stream);
    hipMemsetAsync(xpad, 0, 9469952, stream);

    k_twb<<<1152, 256, 0, stream>>>(w, twb);
    k_prep<<<2048, 256, 0, stream>>>(x, xpad);

    dim3 gconv(64, 8, 4);
    k_mconv<<<gconv, 256, 0, stream>>>(xpad, twb, p2);

    k_stats1<<<512, 256, 0, stream>>>(p2, ps);
    k_ab<<<1, 256, 0, stream>>>(ps, gamma, beta, ab);

    k_route<<<2048, 256, 0, stream>>>(p2, ab, out, out + 4194304);
}